// Round 4
// baseline (6695.920 us; speedup 1.0000x reference)
//
#include <hip/hip_runtime.h>

typedef unsigned int uint;

#define NB 32

// geometry
#define L1N 9216      // 96*96
#define ORGB 75
#define OGRAY 25
#define C1 100
#define PLANE1 2500   // 50*50 padded
#define P1 2304       // 48*48
#define M1 225
#define K1 900
#define K1P 912
#define P2 576        // 24*24
#define M2 625
#define K2 2025
#define K2P 2032
#define N2 484        // 22*22
#define FCN 302500    // 625*484
#define NT1 73728     // 2304*32 merged columns
#define NT2 15488     // 484*32 merged columns

// exact ranks: ceil(percent*N) evaluated in fp64 (all round to these ints)
#define KK0 345600u
#define KK1 115200u
#define KK2 207360u
#define KK3 121000u

// ---- workspace layout (float-element offsets) ----
constexpr size_t O_A     = 0;                                   // D_rgb / D1 / D2
constexpr size_t O_B     = O_A + (size_t)NB*ORGB*L1N;           // D_gray / X2
constexpr size_t O_C     = O_B + (size_t)NB*OGRAY*L1N;          // X1 padded
constexpr size_t O_HIST  = O_C + (size_t)NB*C1*PLANE1;          // 32*2048 uints
constexpr size_t O_STATE = O_HIST + 65536;                      // 4*32 uint2
constexpr size_t O_THR   = O_STATE + 256;                       // 4*32 floats
constexpr size_t O_WSQ1  = O_THR + 128;
constexpr size_t O_WSQ2  = O_WSQ1 + 256;
constexpr size_t O_KOFF1 = O_WSQ2 + 640;                        // 912 ints
constexpr size_t O_KOFF2 = O_KOFF1 + 912;                       // 2032 ints
constexpr size_t O_YMF1  = O_KOFF2 + 2032;                      // 73728 ints
constexpr size_t O_OMAP1 = O_YMF1 + 73728;                      // 73728 ints
constexpr size_t O_YMF2  = O_OMAP1 + 73728;                     // 15488 ints
constexpr size_t O_OMAP2 = O_YMF2 + 15488;                      // 15488 ints
constexpr size_t O_ZP1   = O_OMAP2 + 15488;                     // 32*2500
constexpr size_t O_PSQ1  = O_ZP1 + (size_t)NB*PLANE1;           // 32*2304
constexpr size_t O_Z2    = O_PSQ1 + (size_t)NB*P1;              // 32*576
constexpr size_t O_PSQ2  = O_Z2 + (size_t)NB*P2;                // 32*484
constexpr size_t O_END   = O_PSQ2 + (size_t)NB*N2;              // ~151.7 MB

// ===================== init: zero hist, states, tables, out=bias =====================
__global__ void k_tables(float* ws, const float* fcb, float* out) {
    int i = blockIdx.x*256 + threadIdx.x;
    if (i < 65536) { ((uint*)(ws + O_HIST))[i] = 0u; return; }
    i -= 65536;
    if (i < K1P) {
        int v = 0;
        if (i < K1) { int c = i/9, rm = i%9; v = c*PLANE1 + (rm/3)*50 + (rm%3); }
        ((int*)(ws + O_KOFF1))[i] = v; return;
    }
    i -= K1P;
    if (i < K2P) {
        int v = 0;
        if (i < K2) { int c = i/9, rm = i%9; v = c*P2 + (rm/3)*24 + (rm%3); }
        ((int*)(ws + O_KOFF2))[i] = v; return;
    }
    i -= K2P;
    if (i < NT1) {
        int b = i / P1, p = i % P1;
        ((int*)(ws + O_YMF1))[i]  = b*(C1*PLANE1) + (p/48)*50 + (p%48);
        ((int*)(ws + O_OMAP1))[i] = b*(M1*P1) + p;
        return;
    }
    i -= NT1;
    if (i < NT2) {
        int b = i / N2, p = i % N2;
        ((int*)(ws + O_YMF2))[i]  = b*(M1*P2) + (p/22)*24 + (p%22);
        ((int*)(ws + O_OMAP2))[i] = b*FCN + p;
        return;
    }
    i -= NT2;
    if (i < 320) { out[i] = fcb[i % 10]; return; }
    i -= 320;
    if (i < 128) {
        const uint kks[4] = {KK0, KK1, KK2, KK3};
        ((uint2*)(ws + O_STATE))[i] = make_uint2(0u, kks[i >> 5]);
    }
}

// ===================== per-row squared norms of conv weights =====================
__global__ void k_wsq(const float* c1w, const float* c2w, float* ws) {
    int o = blockIdx.x, lane = threadIdx.x;   // 64 threads
    const float* row; int K; float* dst;
    if (o < M1) { row = c1w + (size_t)o*K1; K = K1; dst = ws + O_WSQ1 + o; }
    else { int oo = o - M1; row = c2w + (size_t)oo*K2; K = K2; dst = ws + O_WSQ2 + oo; }
    float s = 0.f;
    for (int k = lane; k < K; k += 64) { float v = row[k]; s += v*v; }
    #pragma unroll
    for (int off = 32; off; off >>= 1) s += __shfl_down(s, off);
    if (lane == 0) *dst = s;
}

// ===================== stage 1: rgb distance =====================
__global__ void k_rgb_d(const float* __restrict__ x, const float* __restrict__ rgbw,
                        float* __restrict__ D) {
    __shared__ float lw[ORGB*3];
    __shared__ float lwsq[ORGB];
    int tid = threadIdx.x;
    if (tid < ORGB*3) lw[tid] = rgbw[tid];
    __syncthreads();
    if (tid < ORGB) {
        float a = lw[tid*3], b = lw[tid*3+1], c = lw[tid*3+2];
        lwsq[tid] = 25.0f*(a*a + b*b + c*c);
    }
    __syncthreads();
    int p = blockIdx.x*256 + tid;             // 0..9215
    int b = blockIdx.y;
    int y = p / 96, xx = p % 96;
    const float* xb = x + (size_t)b*3*10000;
    float s1_0 = 0, s1_1 = 0, s1_2 = 0, s2 = 0;
    #pragma unroll
    for (int r = 0; r < 5; ++r)
        #pragma unroll
        for (int s = 0; s < 5; ++s) {
            int off = (y+r)*100 + (xx+s);
            float v0 = xb[off], v1 = xb[10000+off], v2 = xb[20000+off];
            s1_0 += v0; s1_1 += v1; s1_2 += v2;
            s2 += v0*v0 + v1*v1 + v2*v2;
        }
    float* Db = D + (size_t)b*ORGB*L1N + p;
    for (int o = 0; o < ORGB; ++o) {
        float dot = lw[o*3]*s1_0 + lw[o*3+1]*s1_1 + lw[o*3+2]*s1_2;
        float d2 = s2 + lwsq[o] - 2.0f*dot;
        Db[(size_t)o*L1N] = sqrtf(fmaxf(d2, 0.0f));
    }
}

// ===================== stage 1: gray distance =====================
__global__ void k_gray_d(const float* __restrict__ x, const float* __restrict__ gw,
                         float* __restrict__ D) {
    __shared__ float lw[625];
    __shared__ float lwsq[25];
    int tid = threadIdx.x;
    for (int i = tid; i < 625; i += 256) lw[i] = gw[i];
    __syncthreads();
    if (tid < 25) {
        float s = 0.f;
        for (int k = 0; k < 25; ++k) { float v = lw[tid*25+k]; s += v*v; }
        lwsq[tid] = s;
    }
    __syncthreads();
    int p = blockIdx.x*256 + tid;
    int b = blockIdx.y;
    int y = p / 96, xx = p % 96;
    const float* xb = x + (size_t)b*3*10000;
    float pv[25]; float psum = 0.f;
    #pragma unroll
    for (int r = 0; r < 5; ++r)
        #pragma unroll
        for (int s = 0; s < 5; ++s) {
            int off = (y+r)*100 + (xx+s);
            float g = 0.2989f*xb[off] + 0.587f*xb[10000+off] + 0.114f*xb[20000+off];
            pv[r*5+s] = g; psum += g*g;
        }
    float* Db = D + (size_t)b*OGRAY*L1N + p;
    for (int o = 0; o < 25; ++o) {
        float dot = 0.f;
        #pragma unroll
        for (int k = 0; k < 25; ++k) dot += lw[o*25+k]*pv[k];
        float d2 = psum + lwsq[o] - 2.0f*dot;
        Db[(size_t)o*L1N] = sqrtf(fmaxf(d2, 0.0f));
    }
}

// ===================== exact rank selection: histogram pass =====================
__global__ void k_hist(const float* __restrict__ d, int perBatch, uint* __restrict__ hist,
                       const uint2* __restrict__ state, int shift, uint pmask) {
    __shared__ uint lh[2048];
    int tid = threadIdx.x;
    for (int i = tid; i < 2048; i += 256) lh[i] = 0u;
    __syncthreads();
    int b = blockIdx.y;
    uint pref = state[b].x;
    const float* db = d + (size_t)b*perBatch;
    for (int i = blockIdx.x*256 + tid; i < perBatch; i += 256*32) {
        uint bits = __float_as_uint(db[i]);
        if ((bits & pmask) == pref)
            atomicAdd(&lh[(bits >> shift) & 2047u], 1u);
    }
    __syncthreads();
    uint* hb = hist + (size_t)b*2048;
    for (int i = tid; i < 2048; i += 256) {
        uint v = lh[i];
        if (v) atomicAdd(&hb[i], v);
    }
}

// ===================== selection: scan + state update (+zero hist) =====================
__global__ void k_scan(uint* __restrict__ hist, uint2* __restrict__ state, int shift,
                       int isFinal, float* __restrict__ thr_out, const float* __restrict__ wcap) {
    __shared__ uint ss[256];
    int b = blockIdx.x, t = threadIdx.x;
    uint* hb = hist + (size_t)b*2048;
    uint bins[8]; uint seg = 0;
    #pragma unroll
    for (int i = 0; i < 8; ++i) { bins[i] = hb[t*8+i]; seg += bins[i]; }
    ss[t] = seg;
    __syncthreads();
    for (int off = 1; off < 256; off <<= 1) {
        uint add = (t >= off) ? ss[t-off] : 0u;
        __syncthreads();
        ss[t] += add;
        __syncthreads();
    }
    uint incl = ss[t], excl = incl - seg;
    uint rank = state[b].y;
    if (excl < rank && rank <= incl) {
        uint c = excl;
        #pragma unroll
        for (int i = 0; i < 8; ++i) {
            c += bins[i];
            if (c >= rank) {
                uint bin = (uint)(t*8+i);
                uint pref = state[b].x | (bin << shift);
                if (isFinal) {
                    thr_out[b] = fminf(__uint_as_float(pref), wcap[0]);
                } else {
                    state[b] = make_uint2(pref, rank - (c - bins[i]));
                }
                break;
            }
        }
    }
    __syncthreads();
    #pragma unroll
    for (int i = 0; i < 8; ++i) hb[t*8+i] = 0u;
}

// ===================== triangle + concat + sfm(2,2) -> padded X1 =====================
__global__ void k_tri_sfm1(const float* __restrict__ Drgb, const float* __restrict__ Dgray,
                           const float* __restrict__ thrA, const float* __restrict__ thrB,
                           const float* __restrict__ w1, float* __restrict__ X1p) {
    int idx = blockIdx.x*256 + threadIdx.x;   // exactly 32*100*2500
    int b = idx / (C1*PLANE1);
    int rem = idx % (C1*PLANE1);
    int c = rem / PLANE1;
    int q = rem % PLANE1;
    int pi = q / 50, pj = q % 50;
    if (pi == 0 || pi == 49 || pj == 0 || pj == 49) { X1p[idx] = 0.f; return; }
    int i = pi - 1, j = pj - 1;
    const float* src; float thr;
    if (c < ORGB) { src = Drgb + ((size_t)b*ORGB + c)*L1N; thr = thrA[b]; }
    else          { src = Dgray + ((size_t)b*OGRAY + (c-ORGB))*L1N; thr = thrB[b]; }
    float invw = 1.0f / w1[0];
    int base = (2*i)*96 + 2*j;
    float d00 = src[base], d01 = src[base+1], d10 = src[base+96], d11 = src[base+97];
    float t00 = d00 > thr ? 0.f : 1.f - d00*invw;
    float t01 = d01 > thr ? 0.f : 1.f - d01*invw;
    float t10 = d10 > thr ? 0.f : 1.f - d10*invw;
    float t11 = d11 > thr ? 0.f : 1.f - d11*invw;
    X1p[idx] = 0.25f*(0.9f*t00 + 0.93f*t01 + 0.96f*t10 + 0.99f*t11);
}

// ===================== channel-sum of squares (padded plane) =====================
__global__ void k_z1(const float* __restrict__ X1p, float* __restrict__ Zp) {
    int idx = blockIdx.x*256 + threadIdx.x;
    if (idx >= NB*PLANE1) return;
    int b = idx / PLANE1, q = idx % PLANE1;
    const float* xb = X1p + (size_t)b*C1*PLANE1 + q;
    float s = 0.f;
    for (int c = 0; c < C1; ++c) { float v = xb[(size_t)c*PLANE1]; s += v*v; }
    Zp[idx] = s;
}

__global__ void k_psq1(const float* __restrict__ Zp, float* __restrict__ psq) {
    int idx = blockIdx.x*256 + threadIdx.x;   // exactly 32*2304
    int b = idx / P1, p = idx % P1;
    int y = p / 48, x = p % 48;
    const float* zb = Zp + (size_t)b*PLANE1;
    float s = 0.f;
    #pragma unroll
    for (int r = 0; r < 3; ++r)
        #pragma unroll
        for (int c = 0; c < 3; ++c) s += zb[(y+r)*50 + x + c];
    psq[idx] = s;
}

// ===================== merged-N implicit-im2col SGEMM =====================
// block tile 128(M) x 256(N), BK=16, micro 8x16 (0.75 B LDS per FMA, was 1.0),
// reg-prefetch double buffer, one barrier per chunk.
// launch_bounds(256,2): VGPR cap 256 — (256,4) caused scratch spilling (R2).
__global__ __launch_bounds__(256, 2) void k_gemm(
        const float* __restrict__ Wm, const float* __restrict__ X,
        const int* __restrict__ koff, const int* __restrict__ ymapF,
        const int* __restrict__ omap, const float* __restrict__ psq,
        const float* __restrict__ wsq, float* __restrict__ Dout,
        int M, int K, int Kpad, int Nper, int NT) {
    __shared__ __align__(16) float As[2*2112];   // [2][16][132]
    __shared__ __align__(16) float Bs[2*4160];   // [2][16][260]
    __shared__ __align__(16) float psl[256];
    __shared__ int outl[256];

    int tid = threadIdx.x;
    int n0 = blockIdx.x*256; if (n0 + 256 > NT) n0 = NT - 256;  // overlap last tile (dup writes identical)
    int m0 = blockIdx.y*128; if (m0 + 128 > M)  m0 = M - 128;   // overlap last tile

    psl[tid] = psq[n0+tid]; outl[tid] = omap[n0+tid];

    // A staging: kkA = k within chunk, rows mA+16*it (all <= m0+127 <= M-1)
    int kkA = tid & 15;
    int mA  = tid >> 4;
    const float* pA = Wm + (size_t)(m0 + mA)*K + kkA;
    // B staging: one column per thread, 16 k's per chunk (koff index is thread-uniform -> s_load)
    const float* pB = X + ymapF[n0 + tid];

    float acc[8][16];
    #pragma unroll
    for (int i = 0; i < 8; ++i)
        #pragma unroll
        for (int j = 0; j < 16; ++j) acc[i][j] = 0.f;

    float aPre[8], bPre[16];
    #pragma unroll
    for (int it = 0; it < 8; ++it) aPre[it] = pA[it*16*K];
    #pragma unroll
    for (int j = 0; j < 16; ++j)   bPre[j] = pB[koff[j]];

    int tn = tid & 15, tm = tid >> 4;
    int nch = Kpad >> 4;
    int curA = 0, curB = 0;
    for (int kc = 0; kc < nch; ++kc) {
        float* Asw = As + curA;
        float* Bsw = Bs + curB;
        #pragma unroll
        for (int it = 0; it < 8; ++it)  Asw[kkA*132 + mA + 16*it] = aPre[it];
        #pragma unroll
        for (int j = 0; j < 16; ++j)    Bsw[j*260 + tid]          = bPre[j];
        __syncthreads();
        if (kc + 1 < nch) {
            int kb = (kc+1)*16;
            bool aok = (kb + kkA) < K;          // only false in the padded tail chunk
            #pragma unroll
            for (int it = 0; it < 8; ++it)
                aPre[it] = aok ? pA[it*16*K + kb] : 0.f;
            #pragma unroll
            for (int j = 0; j < 16; ++j)
                bPre[j] = pB[koff[kb + j]];
        }
        const float4* A4 = (const float4*)(As + curA);
        const float4* B4 = (const float4*)(Bs + curB);
        #pragma unroll
        for (int kk = 0; kk < 16; ++kk) {
            float4 a0 = A4[kk*33 + tm],          a1 = A4[kk*33 + 16 + tm];
            float4 b0 = B4[kk*65 + tn],          b1 = B4[kk*65 + 16 + tn];
            float4 b2 = B4[kk*65 + 32 + tn],     b3 = B4[kk*65 + 48 + tn];
            float av[8]  = {a0.x,a0.y,a0.z,a0.w,a1.x,a1.y,a1.z,a1.w};
            float bv[16] = {b0.x,b0.y,b0.z,b0.w,b1.x,b1.y,b1.z,b1.w,
                            b2.x,b2.y,b2.z,b2.w,b3.x,b3.y,b3.z,b3.w};
            #pragma unroll
            for (int i = 0; i < 8; ++i)
                #pragma unroll
                for (int j = 0; j < 16; ++j) acc[i][j] += av[i]*bv[j];
        }
        curA ^= 2112; curB ^= 4160;
        // single barrier per chunk is sufficient: writes always target the buffer
        // whose last readers finished before the previous barrier.
    }

    // epilogue: per thread 8 rows x 4 col-groups of 4 -> float4 stores
    #pragma unroll
    for (int i = 0; i < 8; ++i) {
        int gm = m0 + tm*4 + (i&3) + ((i>>2)<<6);
        float wq = wsq[gm];
        size_t ra = (size_t)gm * Nper;
        #pragma unroll
        for (int g = 0; g < 4; ++g) {
            int jn = tn*4 + (g<<6);
            float4 pq = *(const float4*)&psl[jn];
            size_t ob = (size_t)outl[jn];
            float4 r;
            r.x = sqrtf(fmaxf(pq.x + wq - 2.0f*acc[i][g*4+0], 0.f));
            r.y = sqrtf(fmaxf(pq.y + wq - 2.0f*acc[i][g*4+1], 0.f));
            r.z = sqrtf(fmaxf(pq.z + wq - 2.0f*acc[i][g*4+2], 0.f));
            r.w = sqrtf(fmaxf(pq.w + wq - 2.0f*acc[i][g*4+3], 0.f));
            *(float4*)&Dout[ob + ra] = r;
        }
    }
}

// ===================== triangle + sfm(2,2) after conv1 =====================
__global__ void k_tri_sfm2(const float* __restrict__ D1, const float* __restrict__ thr2,
                           const float* __restrict__ w2, float* __restrict__ X2) {
    int idx = blockIdx.x*256 + threadIdx.x;   // exactly 32*225*576
    int b = idx / (M1*P2);
    int rem = idx % (M1*P2);
    int c = rem / P2, q = rem % P2;
    int i = q / 24, j = q % 24;
    const float* src = D1 + ((size_t)b*M1 + c)*P1;
    float thr = thr2[b], invw = 1.0f / w2[0];
    int base = (2*i)*48 + 2*j;
    float d00 = src[base], d01 = src[base+1], d10 = src[base+48], d11 = src[base+49];
    float t00 = d00 > thr ? 0.f : 1.f - d00*invw;
    float t01 = d01 > thr ? 0.f : 1.f - d01*invw;
    float t10 = d10 > thr ? 0.f : 1.f - d10*invw;
    float t11 = d11 > thr ? 0.f : 1.f - d11*invw;
    X2[idx] = 0.25f*(0.9f*t00 + 0.93f*t01 + 0.96f*t10 + 0.99f*t11);
}

__global__ void k_z2(const float* __restrict__ X2, float* __restrict__ Z2) {
    int idx = blockIdx.x*256 + threadIdx.x;
    if (idx >= NB*P2) return;
    int b = idx / P2, q = idx % P2;
    const float* xb = X2 + (size_t)b*M1*P2 + q;
    float s = 0.f;
    for (int c = 0; c < M1; ++c) { float v = xb[(size_t)c*P2]; s += v*v; }
    Z2[idx] = s;
}

__global__ void k_psq2(const float* __restrict__ Z2, float* __restrict__ psq) {
    int idx = blockIdx.x*256 + threadIdx.x;
    if (idx >= NB*N2) return;
    int b = idx / N2, p = idx % N2;
    int y = p / 22, x = p % 22;
    const float* zb = Z2 + (size_t)b*P2;
    float s = 0.f;
    #pragma unroll
    for (int r = 0; r < 3; ++r)
        #pragma unroll
        for (int c = 0; c < 3; ++c) s += zb[(y+r)*24 + x + c];
    psq[idx] = s;
}

// ===================== triangle + FC =====================
__global__ void k_fc(const float* __restrict__ D2, const float* __restrict__ fcw,
                     const float* __restrict__ thr3, const float* __restrict__ w3,
                     float* __restrict__ out) {
    int tid = threadIdx.x, b = blockIdx.y;
    float thr = thr3[b];
    float invw = 1.0f / w3[0];
    const float* db = D2 + (size_t)b*FCN;
    float acc[10];
    #pragma unroll
    for (int o = 0; o < 10; ++o) acc[o] = 0.f;
    int base = blockIdx.x*2048;
    #pragma unroll
    for (int it = 0; it < 8; ++it) {
        int p = base + it*256 + tid;
        if (p < FCN) {
            float v = db[p];
            float tv = v > thr ? 0.f : 1.f - v*invw;
            #pragma unroll
            for (int o = 0; o < 10; ++o) acc[o] += tv * fcw[(size_t)o*FCN + p];
        }
    }
    #pragma unroll
    for (int o = 0; o < 10; ++o)
        #pragma unroll
        for (int off = 32; off; off >>= 1) acc[o] += __shfl_down(acc[o], off);
    __shared__ float red[4][10];
    int lane = tid & 63, wid = tid >> 6;
    if (lane == 0) {
        #pragma unroll
        for (int o = 0; o < 10; ++o) red[wid][o] = acc[o];
    }
    __syncthreads();
    if (tid < 10) {
        float s = red[0][tid] + red[1][tid] + red[2][tid] + red[3][tid];
        atomicAdd(&out[b*10 + tid], s);
    }
}

// ===================== launch =====================
extern "C" void kernel_launch(void* const* d_in, const int* in_sizes, int n_in,
                              void* d_out, int out_size, void* d_ws, size_t ws_size,
                              hipStream_t stream) {
    const float* x    = (const float*)d_in[0];
    const float* rgbw = (const float*)d_in[1];
    const float* gryw = (const float*)d_in[2];
    const float* c1w  = (const float*)d_in[3];
    const float* c2w  = (const float*)d_in[4];
    const float* fcw  = (const float*)d_in[5];
    const float* fcb  = (const float*)d_in[6];
    const float* w1   = (const float*)d_in[7];
    const float* w2   = (const float*)d_in[8];
    const float* w3   = (const float*)d_in[9];
    float* out = (float*)d_out;
    float* ws  = (float*)d_ws;

    float* Drgb  = ws + O_A;
    float* Dgray = ws + O_B;
    float* X1p   = ws + O_C;
    uint*  hist  = (uint*)(ws + O_HIST);
    uint2* state = (uint2*)(ws + O_STATE);
    float* thr   = ws + O_THR;
    int* koff1 = (int*)(ws + O_KOFF1);
    int* koff2 = (int*)(ws + O_KOFF2);
    int* ymf1  = (int*)(ws + O_YMF1);
    int* omap1 = (int*)(ws + O_OMAP1);
    int* ymf2  = (int*)(ws + O_YMF2);
    int* omap2 = (int*)(ws + O_OMAP2);

    // total init threads: 65536+912+2032+73728+15488+320+128 = 158144 -> 618 blocks
    k_tables<<<618, 256, 0, stream>>>(ws, fcb, out);
    k_wsq<<<M1 + M2, 64, 0, stream>>>(c1w, c2w, ws);
    k_rgb_d<<<dim3(36, 32), 256, 0, stream>>>(x, rgbw, Drgb);
    k_gray_d<<<dim3(36, 32), 256, 0, stream>>>(x, gryw, Dgray);

    auto sel = [&](const float* dptr, int perBatch, uint2* st, float* thro, const float* wc) {
        const int shifts[3] = {21, 10, 0};
        const uint masks[3] = {0u, 0xFFE00000u, 0xFFFFFC00u};
        for (int p = 0; p < 3; ++p) {
            k_hist<<<dim3(32, 32), 256, 0, stream>>>(dptr, perBatch, hist, st, shifts[p], masks[p]);
            k_scan<<<32, 256, 0, stream>>>(hist, st, shifts[p], p == 2, thro, wc);
        }
    };

    sel(Drgb, ORGB*L1N, state + 0,  thr + 0,  w1);
    sel(Dgray, OGRAY*L1N, state + 32, thr + 32, w1);

    k_tri_sfm1<<<31250, 256, 0, stream>>>(Drgb, Dgray, thr + 0, thr + 32, w1, X1p);
    k_z1<<<313, 256, 0, stream>>>(X1p, ws + O_ZP1);
    k_psq1<<<288, 256, 0, stream>>>(ws + O_ZP1, ws + O_PSQ1);

    float* D1 = ws + O_A;
    k_gemm<<<dim3(NT1/256, 2), 256, 0, stream>>>(c1w, X1p, koff1, ymf1, omap1,
        ws + O_PSQ1, ws + O_WSQ1, D1, M1, K1, K1P, P1, NT1);

    sel(D1, M1*P1, state + 64, thr + 64, w2);

    float* X2 = ws + O_B;
    k_tri_sfm2<<<16200, 256, 0, stream>>>(D1, thr + 64, w2, X2);
    k_z2<<<72, 256, 0, stream>>>(X2, ws + O_Z2);
    k_psq2<<<61, 256, 0, stream>>>(ws + O_Z2, ws + O_PSQ2);

    float* D2 = ws + O_A;
    k_gemm<<<dim3((NT2 + 255)/256, 5), 256, 0, stream>>>(c2w, X2, koff2, ymf2, omap2,
        ws + O_PSQ2, ws + O_WSQ2, D2, M2, K2, K2P, N2, NT2);

    sel(D2, FCN, state + 96, thr + 96, w3);

    k_fc<<<dim3(148, 32), 256, 0, stream>>>(D2, fcw, thr + 96, w3, out);
}

// Round 5
// 1988.948 us; speedup vs baseline: 3.3666x; 3.3666x over previous
//
#include <hip/hip_runtime.h>

typedef unsigned int uint;

#define NB 32

// geometry
#define L1N 9216      // 96*96
#define ORGB 75
#define OGRAY 25
#define C1 100
#define PLANE1 2500   // 50*50 padded
#define P1 2304       // 48*48
#define M1 225
#define K1 900
#define K1P 912
#define P2 576        // 24*24
#define M2 625
#define K2 2025
#define K2P 2032
#define N2 484        // 22*22
#define FCN 302500    // 625*484
#define NT1 73728     // 2304*32 merged columns
#define NT2 15488     // 484*32 merged columns

// exact ranks: ceil(percent*N) evaluated in fp64 (all round to these ints)
#define KK0 345600u
#define KK1 115200u
#define KK2 207360u
#define KK3 121000u

// ---- workspace layout (float-element offsets) ----
constexpr size_t O_A     = 0;                                   // D_rgb / D1 / D2
constexpr size_t O_B     = O_A + (size_t)NB*ORGB*L1N;           // D_gray / X2
constexpr size_t O_C     = O_B + (size_t)NB*OGRAY*L1N;          // X1 padded
constexpr size_t O_HIST  = O_C + (size_t)NB*C1*PLANE1;          // 32*2048 uints
constexpr size_t O_STATE = O_HIST + 65536;                      // 4*32 uint2
constexpr size_t O_THR   = O_STATE + 256;                       // 4*32 floats
constexpr size_t O_WSQ1  = O_THR + 128;
constexpr size_t O_WSQ2  = O_WSQ1 + 256;
constexpr size_t O_KOFF1 = O_WSQ2 + 640;                        // 912 ints
constexpr size_t O_KOFF2 = O_KOFF1 + 912;                       // 2032 ints
constexpr size_t O_YMF1  = O_KOFF2 + 2032;                      // 73728 ints
constexpr size_t O_OMAP1 = O_YMF1 + 73728;                      // 73728 ints
constexpr size_t O_YMF2  = O_OMAP1 + 73728;                     // 15488 ints
constexpr size_t O_OMAP2 = O_YMF2 + 15488;                      // 15488 ints
constexpr size_t O_ZP1   = O_OMAP2 + 15488;                     // 32*2500
constexpr size_t O_PSQ1  = O_ZP1 + (size_t)NB*PLANE1;           // 32*2304
constexpr size_t O_Z2    = O_PSQ1 + (size_t)NB*P1;              // 32*576
constexpr size_t O_PSQ2  = O_Z2 + (size_t)NB*P2;                // 32*484
constexpr size_t O_END   = O_PSQ2 + (size_t)NB*N2;              // ~151.7 MB

// ===================== init: zero hist, states, tables, out=bias =====================
__global__ void k_tables(float* ws, const float* fcb, float* out) {
    int i = blockIdx.x*256 + threadIdx.x;
    if (i < 65536) { ((uint*)(ws + O_HIST))[i] = 0u; return; }
    i -= 65536;
    if (i < K1P) {
        int v = 0;
        if (i < K1) { int c = i/9, rm = i%9; v = c*PLANE1 + (rm/3)*50 + (rm%3); }
        ((int*)(ws + O_KOFF1))[i] = v; return;
    }
    i -= K1P;
    if (i < K2P) {
        int v = 0;
        if (i < K2) { int c = i/9, rm = i%9; v = c*P2 + (rm/3)*24 + (rm%3); }
        ((int*)(ws + O_KOFF2))[i] = v; return;
    }
    i -= K2P;
    if (i < NT1) {
        int b = i / P1, p = i % P1;
        ((int*)(ws + O_YMF1))[i]  = b*(C1*PLANE1) + (p/48)*50 + (p%48);
        ((int*)(ws + O_OMAP1))[i] = b*(M1*P1) + p;
        return;
    }
    i -= NT1;
    if (i < NT2) {
        int b = i / N2, p = i % N2;
        ((int*)(ws + O_YMF2))[i]  = b*(M1*P2) + (p/22)*24 + (p%22);
        ((int*)(ws + O_OMAP2))[i] = b*FCN + p;
        return;
    }
    i -= NT2;
    if (i < 320) { out[i] = fcb[i % 10]; return; }
    i -= 320;
    if (i < 128) {
        const uint kks[4] = {KK0, KK1, KK2, KK3};
        ((uint2*)(ws + O_STATE))[i] = make_uint2(0u, kks[i >> 5]);
    }
}

// ===================== per-row squared norms of conv weights =====================
__global__ void k_wsq(const float* c1w, const float* c2w, float* ws) {
    int o = blockIdx.x, lane = threadIdx.x;   // 64 threads
    const float* row; int K; float* dst;
    if (o < M1) { row = c1w + (size_t)o*K1; K = K1; dst = ws + O_WSQ1 + o; }
    else { int oo = o - M1; row = c2w + (size_t)oo*K2; K = K2; dst = ws + O_WSQ2 + oo; }
    float s = 0.f;
    for (int k = lane; k < K; k += 64) { float v = row[k]; s += v*v; }
    #pragma unroll
    for (int off = 32; off; off >>= 1) s += __shfl_down(s, off);
    if (lane == 0) *dst = s;
}

// ===================== stage 1: rgb distance =====================
__global__ void k_rgb_d(const float* __restrict__ x, const float* __restrict__ rgbw,
                        float* __restrict__ D) {
    __shared__ float lw[ORGB*3];
    __shared__ float lwsq[ORGB];
    int tid = threadIdx.x;
    if (tid < ORGB*3) lw[tid] = rgbw[tid];
    __syncthreads();
    if (tid < ORGB) {
        float a = lw[tid*3], b = lw[tid*3+1], c = lw[tid*3+2];
        lwsq[tid] = 25.0f*(a*a + b*b + c*c);
    }
    __syncthreads();
    int p = blockIdx.x*256 + tid;             // 0..9215
    int b = blockIdx.y;
    int y = p / 96, xx = p % 96;
    const float* xb = x + (size_t)b*3*10000;
    float s1_0 = 0, s1_1 = 0, s1_2 = 0, s2 = 0;
    #pragma unroll
    for (int r = 0; r < 5; ++r)
        #pragma unroll
        for (int s = 0; s < 5; ++s) {
            int off = (y+r)*100 + (xx+s);
            float v0 = xb[off], v1 = xb[10000+off], v2 = xb[20000+off];
            s1_0 += v0; s1_1 += v1; s1_2 += v2;
            s2 += v0*v0 + v1*v1 + v2*v2;
        }
    float* Db = D + (size_t)b*ORGB*L1N + p;
    for (int o = 0; o < ORGB; ++o) {
        float dot = lw[o*3]*s1_0 + lw[o*3+1]*s1_1 + lw[o*3+2]*s1_2;
        float d2 = s2 + lwsq[o] - 2.0f*dot;
        Db[(size_t)o*L1N] = sqrtf(fmaxf(d2, 0.0f));
    }
}

// ===================== stage 1: gray distance =====================
__global__ void k_gray_d(const float* __restrict__ x, const float* __restrict__ gw,
                         float* __restrict__ D) {
    __shared__ float lw[625];
    __shared__ float lwsq[25];
    int tid = threadIdx.x;
    for (int i = tid; i < 625; i += 256) lw[i] = gw[i];
    __syncthreads();
    if (tid < 25) {
        float s = 0.f;
        for (int k = 0; k < 25; ++k) { float v = lw[tid*25+k]; s += v*v; }
        lwsq[tid] = s;
    }
    __syncthreads();
    int p = blockIdx.x*256 + tid;
    int b = blockIdx.y;
    int y = p / 96, xx = p % 96;
    const float* xb = x + (size_t)b*3*10000;
    float pv[25]; float psum = 0.f;
    #pragma unroll
    for (int r = 0; r < 5; ++r)
        #pragma unroll
        for (int s = 0; s < 5; ++s) {
            int off = (y+r)*100 + (xx+s);
            float g = 0.2989f*xb[off] + 0.587f*xb[10000+off] + 0.114f*xb[20000+off];
            pv[r*5+s] = g; psum += g*g;
        }
    float* Db = D + (size_t)b*OGRAY*L1N + p;
    for (int o = 0; o < 25; ++o) {
        float dot = 0.f;
        #pragma unroll
        for (int k = 0; k < 25; ++k) dot += lw[o*25+k]*pv[k];
        float d2 = psum + lwsq[o] - 2.0f*dot;
        Db[(size_t)o*L1N] = sqrtf(fmaxf(d2, 0.0f));
    }
}

// ===================== exact rank selection: histogram pass =====================
__global__ void k_hist(const float* __restrict__ d, int perBatch, uint* __restrict__ hist,
                       const uint2* __restrict__ state, int shift, uint pmask) {
    __shared__ uint lh[2048];
    int tid = threadIdx.x;
    for (int i = tid; i < 2048; i += 256) lh[i] = 0u;
    __syncthreads();
    int b = blockIdx.y;
    uint pref = state[b].x;
    const float* db = d + (size_t)b*perBatch;
    for (int i = blockIdx.x*256 + tid; i < perBatch; i += 256*32) {
        uint bits = __float_as_uint(db[i]);
        if ((bits & pmask) == pref)
            atomicAdd(&lh[(bits >> shift) & 2047u], 1u);
    }
    __syncthreads();
    uint* hb = hist + (size_t)b*2048;
    for (int i = tid; i < 2048; i += 256) {
        uint v = lh[i];
        if (v) atomicAdd(&hb[i], v);
    }
}

// ===================== selection: scan + state update (+zero hist) =====================
__global__ void k_scan(uint* __restrict__ hist, uint2* __restrict__ state, int shift,
                       int isFinal, float* __restrict__ thr_out, const float* __restrict__ wcap) {
    __shared__ uint ss[256];
    int b = blockIdx.x, t = threadIdx.x;
    uint* hb = hist + (size_t)b*2048;
    uint bins[8]; uint seg = 0;
    #pragma unroll
    for (int i = 0; i < 8; ++i) { bins[i] = hb[t*8+i]; seg += bins[i]; }
    ss[t] = seg;
    __syncthreads();
    for (int off = 1; off < 256; off <<= 1) {
        uint add = (t >= off) ? ss[t-off] : 0u;
        __syncthreads();
        ss[t] += add;
        __syncthreads();
    }
    uint incl = ss[t], excl = incl - seg;
    uint rank = state[b].y;
    if (excl < rank && rank <= incl) {
        uint c = excl;
        #pragma unroll
        for (int i = 0; i < 8; ++i) {
            c += bins[i];
            if (c >= rank) {
                uint bin = (uint)(t*8+i);
                uint pref = state[b].x | (bin << shift);
                if (isFinal) {
                    thr_out[b] = fminf(__uint_as_float(pref), wcap[0]);
                } else {
                    state[b] = make_uint2(pref, rank - (c - bins[i]));
                }
                break;
            }
        }
    }
    __syncthreads();
    #pragma unroll
    for (int i = 0; i < 8; ++i) hb[t*8+i] = 0u;
}

// ===================== triangle + concat + sfm(2,2) -> padded X1 =====================
__global__ void k_tri_sfm1(const float* __restrict__ Drgb, const float* __restrict__ Dgray,
                           const float* __restrict__ thrA, const float* __restrict__ thrB,
                           const float* __restrict__ w1, float* __restrict__ X1p) {
    int idx = blockIdx.x*256 + threadIdx.x;   // exactly 32*100*2500
    int b = idx / (C1*PLANE1);
    int rem = idx % (C1*PLANE1);
    int c = rem / PLANE1;
    int q = rem % PLANE1;
    int pi = q / 50, pj = q % 50;
    if (pi == 0 || pi == 49 || pj == 0 || pj == 49) { X1p[idx] = 0.f; return; }
    int i = pi - 1, j = pj - 1;
    const float* src; float thr;
    if (c < ORGB) { src = Drgb + ((size_t)b*ORGB + c)*L1N; thr = thrA[b]; }
    else          { src = Dgray + ((size_t)b*OGRAY + (c-ORGB))*L1N; thr = thrB[b]; }
    float invw = 1.0f / w1[0];
    int base = (2*i)*96 + 2*j;
    float d00 = src[base], d01 = src[base+1], d10 = src[base+96], d11 = src[base+97];
    float t00 = d00 > thr ? 0.f : 1.f - d00*invw;
    float t01 = d01 > thr ? 0.f : 1.f - d01*invw;
    float t10 = d10 > thr ? 0.f : 1.f - d10*invw;
    float t11 = d11 > thr ? 0.f : 1.f - d11*invw;
    X1p[idx] = 0.25f*(0.9f*t00 + 0.93f*t01 + 0.96f*t10 + 0.99f*t11);
}

// ===================== channel-sum of squares (padded plane) =====================
__global__ void k_z1(const float* __restrict__ X1p, float* __restrict__ Zp) {
    int idx = blockIdx.x*256 + threadIdx.x;
    if (idx >= NB*PLANE1) return;
    int b = idx / PLANE1, q = idx % PLANE1;
    const float* xb = X1p + (size_t)b*C1*PLANE1 + q;
    float s = 0.f;
    for (int c = 0; c < C1; ++c) { float v = xb[(size_t)c*PLANE1]; s += v*v; }
    Zp[idx] = s;
}

__global__ void k_psq1(const float* __restrict__ Zp, float* __restrict__ psq) {
    int idx = blockIdx.x*256 + threadIdx.x;   // exactly 32*2304
    int b = idx / P1, p = idx % P1;
    int y = p / 48, x = p % 48;
    const float* zb = Zp + (size_t)b*PLANE1;
    float s = 0.f;
    #pragma unroll
    for (int r = 0; r < 3; ++r)
        #pragma unroll
        for (int c = 0; c < 3; ++c) s += zb[(y+r)*50 + x + c];
    psq[idx] = s;
}

// ===================== merged-N implicit-im2col SGEMM =====================
// block tile 128(M) x 256(N), BK=16, micro 8x16 (0.75 B LDS per FMA),
// reg-prefetch double buffer, one barrier per chunk.
// launch_bounds(256,1): min-waves 1 -> VGPR cap 512, stops the allocator's
// forced-occupancy spilling (R2: cap 128 spilled; R4: heuristic chose 128
// and spilled despite cap 256). kk loop unrolled x4 to keep the scheduling
// window at 512 FMAs (full 2048-FMA unroll blew up live-range estimates).
__global__ __launch_bounds__(256, 1) void k_gemm(
        const float* __restrict__ Wm, const float* __restrict__ X,
        const int* __restrict__ koff, const int* __restrict__ ymapF,
        const int* __restrict__ omap, const float* __restrict__ psq,
        const float* __restrict__ wsq, float* __restrict__ Dout,
        int M, int K, int Kpad, int Nper, int NT) {
    __shared__ __align__(16) float As[2*2112];   // [2][16][132]
    __shared__ __align__(16) float Bs[2*4160];   // [2][16][260]
    __shared__ __align__(16) float psl[256];
    __shared__ int outl[256];

    int tid = threadIdx.x;
    int n0 = blockIdx.x*256; if (n0 + 256 > NT) n0 = NT - 256;  // overlap last tile (dup writes identical)
    int m0 = blockIdx.y*128; if (m0 + 128 > M)  m0 = M - 128;   // overlap last tile

    psl[tid] = psq[n0+tid]; outl[tid] = omap[n0+tid];

    // A staging: kkA = k within chunk, rows mA+16*it (all <= m0+127 <= M-1)
    int kkA = tid & 15;
    int mA  = tid >> 4;
    const float* pA = Wm + (size_t)(m0 + mA)*K + kkA;
    // B staging: one column per thread, 16 k's per chunk (koff index is thread-uniform -> s_load)
    const float* pB = X + ymapF[n0 + tid];

    float acc[8][16];
    #pragma unroll
    for (int i = 0; i < 8; ++i)
        #pragma unroll
        for (int j = 0; j < 16; ++j) acc[i][j] = 0.f;

    float aPre[8], bPre[16];
    #pragma unroll
    for (int it = 0; it < 8; ++it) aPre[it] = pA[it*16*K];
    #pragma unroll
    for (int j = 0; j < 16; ++j)   bPre[j] = pB[koff[j]];

    int tn = tid & 15, tm = tid >> 4;
    int nch = Kpad >> 4;
    int curA = 0, curB = 0;
    for (int kc = 0; kc < nch; ++kc) {
        float* Asw = As + curA;
        float* Bsw = Bs + curB;
        #pragma unroll
        for (int it = 0; it < 8; ++it)  Asw[kkA*132 + mA + 16*it] = aPre[it];
        #pragma unroll
        for (int j = 0; j < 16; ++j)    Bsw[j*260 + tid]          = bPre[j];
        __syncthreads();
        if (kc + 1 < nch) {
            int kb = (kc+1)*16;
            bool aok = (kb + kkA) < K;          // only false in the padded tail chunk
            #pragma unroll
            for (int it = 0; it < 8; ++it)
                aPre[it] = aok ? pA[it*16*K + kb] : 0.f;
            #pragma unroll
            for (int j = 0; j < 16; ++j)
                bPre[j] = pB[koff[kb + j]];
        }
        const float4* A4 = (const float4*)(As + curA);
        const float4* B4 = (const float4*)(Bs + curB);
        #pragma unroll 4
        for (int kk = 0; kk < 16; ++kk) {
            float4 a0 = A4[kk*33 + tm],          a1 = A4[kk*33 + 16 + tm];
            float4 b0 = B4[kk*65 + tn],          b1 = B4[kk*65 + 16 + tn];
            float4 b2 = B4[kk*65 + 32 + tn],     b3 = B4[kk*65 + 48 + tn];
            float av[8]  = {a0.x,a0.y,a0.z,a0.w,a1.x,a1.y,a1.z,a1.w};
            float bv[16] = {b0.x,b0.y,b0.z,b0.w,b1.x,b1.y,b1.z,b1.w,
                            b2.x,b2.y,b2.z,b2.w,b3.x,b3.y,b3.z,b3.w};
            #pragma unroll
            for (int i = 0; i < 8; ++i)
                #pragma unroll
                for (int j = 0; j < 16; ++j) acc[i][j] += av[i]*bv[j];
        }
        curA ^= 2112; curB ^= 4160;
        // single barrier per chunk is sufficient: writes always target the buffer
        // whose last readers finished before the previous barrier.
    }

    // epilogue: per thread 8 rows x 4 col-groups of 4 -> float4 stores
    #pragma unroll
    for (int i = 0; i < 8; ++i) {
        int gm = m0 + tm*4 + (i&3) + ((i>>2)<<6);
        float wq = wsq[gm];
        size_t ra = (size_t)gm * Nper;
        #pragma unroll
        for (int g = 0; g < 4; ++g) {
            int jn = tn*4 + (g<<6);
            float4 pq = *(const float4*)&psl[jn];
            size_t ob = (size_t)outl[jn];
            float4 r;
            r.x = sqrtf(fmaxf(pq.x + wq - 2.0f*acc[i][g*4+0], 0.f));
            r.y = sqrtf(fmaxf(pq.y + wq - 2.0f*acc[i][g*4+1], 0.f));
            r.z = sqrtf(fmaxf(pq.z + wq - 2.0f*acc[i][g*4+2], 0.f));
            r.w = sqrtf(fmaxf(pq.w + wq - 2.0f*acc[i][g*4+3], 0.f));
            *(float4*)&Dout[ob + ra] = r;
        }
    }
}

// ===================== triangle + sfm(2,2) after conv1 =====================
__global__ void k_tri_sfm2(const float* __restrict__ D1, const float* __restrict__ thr2,
                           const float* __restrict__ w2, float* __restrict__ X2) {
    int idx = blockIdx.x*256 + threadIdx.x;   // exactly 32*225*576
    int b = idx / (M1*P2);
    int rem = idx % (M1*P2);
    int c = rem / P2, q = rem % P2;
    int i = q / 24, j = q % 24;
    const float* src = D1 + ((size_t)b*M1 + c)*P1;
    float thr = thr2[b], invw = 1.0f / w2[0];
    int base = (2*i)*48 + 2*j;
    float d00 = src[base], d01 = src[base+1], d10 = src[base+48], d11 = src[base+49];
    float t00 = d00 > thr ? 0.f : 1.f - d00*invw;
    float t01 = d01 > thr ? 0.f : 1.f - d01*invw;
    float t10 = d10 > thr ? 0.f : 1.f - d10*invw;
    float t11 = d11 > thr ? 0.f : 1.f - d11*invw;
    X2[idx] = 0.25f*(0.9f*t00 + 0.93f*t01 + 0.96f*t10 + 0.99f*t11);
}

__global__ void k_z2(const float* __restrict__ X2, float* __restrict__ Z2) {
    int idx = blockIdx.x*256 + threadIdx.x;
    if (idx >= NB*P2) return;
    int b = idx / P2, q = idx % P2;
    const float* xb = X2 + (size_t)b*M1*P2 + q;
    float s = 0.f;
    for (int c = 0; c < M1; ++c) { float v = xb[(size_t)c*P2]; s += v*v; }
    Z2[idx] = s;
}

__global__ void k_psq2(const float* __restrict__ Z2, float* __restrict__ psq) {
    int idx = blockIdx.x*256 + threadIdx.x;
    if (idx >= NB*N2) return;
    int b = idx / N2, p = idx % N2;
    int y = p / 22, x = p % 22;
    const float* zb = Z2 + (size_t)b*P2;
    float s = 0.f;
    #pragma unroll
    for (int r = 0; r < 3; ++r)
        #pragma unroll
        for (int c = 0; c < 3; ++c) s += zb[(y+r)*24 + x + c];
    psq[idx] = s;
}

// ===================== triangle + FC =====================
__global__ void k_fc(const float* __restrict__ D2, const float* __restrict__ fcw,
                     const float* __restrict__ thr3, const float* __restrict__ w3,
                     float* __restrict__ out) {
    int tid = threadIdx.x, b = blockIdx.y;
    float thr = thr3[b];
    float invw = 1.0f / w3[0];
    const float* db = D2 + (size_t)b*FCN;
    float acc[10];
    #pragma unroll
    for (int o = 0; o < 10; ++o) acc[o] = 0.f;
    int base = blockIdx.x*2048;
    #pragma unroll
    for (int it = 0; it < 8; ++it) {
        int p = base + it*256 + tid;
        if (p < FCN) {
            float v = db[p];
            float tv = v > thr ? 0.f : 1.f - v*invw;
            #pragma unroll
            for (int o = 0; o < 10; ++o) acc[o] += tv * fcw[(size_t)o*FCN + p];
        }
    }
    #pragma unroll
    for (int o = 0; o < 10; ++o)
        #pragma unroll
        for (int off = 32; off; off >>= 1) acc[o] += __shfl_down(acc[o], off);
    __shared__ float red[4][10];
    int lane = tid & 63, wid = tid >> 6;
    if (lane == 0) {
        #pragma unroll
        for (int o = 0; o < 10; ++o) red[wid][o] = acc[o];
    }
    __syncthreads();
    if (tid < 10) {
        float s = red[0][tid] + red[1][tid] + red[2][tid] + red[3][tid];
        atomicAdd(&out[b*10 + tid], s);
    }
}

// ===================== launch =====================
extern "C" void kernel_launch(void* const* d_in, const int* in_sizes, int n_in,
                              void* d_out, int out_size, void* d_ws, size_t ws_size,
                              hipStream_t stream) {
    const float* x    = (const float*)d_in[0];
    const float* rgbw = (const float*)d_in[1];
    const float* gryw = (const float*)d_in[2];
    const float* c1w  = (const float*)d_in[3];
    const float* c2w  = (const float*)d_in[4];
    const float* fcw  = (const float*)d_in[5];
    const float* fcb  = (const float*)d_in[6];
    const float* w1   = (const float*)d_in[7];
    const float* w2   = (const float*)d_in[8];
    const float* w3   = (const float*)d_in[9];
    float* out = (float*)d_out;
    float* ws  = (float*)d_ws;

    float* Drgb  = ws + O_A;
    float* Dgray = ws + O_B;
    float* X1p   = ws + O_C;
    uint*  hist  = (uint*)(ws + O_HIST);
    uint2* state = (uint2*)(ws + O_STATE);
    float* thr   = ws + O_THR;
    int* koff1 = (int*)(ws + O_KOFF1);
    int* koff2 = (int*)(ws + O_KOFF2);
    int* ymf1  = (int*)(ws + O_YMF1);
    int* omap1 = (int*)(ws + O_OMAP1);
    int* ymf2  = (int*)(ws + O_YMF2);
    int* omap2 = (int*)(ws + O_OMAP2);

    // total init threads: 65536+912+2032+73728+15488+320+128 = 158144 -> 618 blocks
    k_tables<<<618, 256, 0, stream>>>(ws, fcb, out);
    k_wsq<<<M1 + M2, 64, 0, stream>>>(c1w, c2w, ws);
    k_rgb_d<<<dim3(36, 32), 256, 0, stream>>>(x, rgbw, Drgb);
    k_gray_d<<<dim3(36, 32), 256, 0, stream>>>(x, gryw, Dgray);

    auto sel = [&](const float* dptr, int perBatch, uint2* st, float* thro, const float* wc) {
        const int shifts[3] = {21, 10, 0};
        const uint masks[3] = {0u, 0xFFE00000u, 0xFFFFFC00u};
        for (int p = 0; p < 3; ++p) {
            k_hist<<<dim3(32, 32), 256, 0, stream>>>(dptr, perBatch, hist, st, shifts[p], masks[p]);
            k_scan<<<32, 256, 0, stream>>>(hist, st, shifts[p], p == 2, thro, wc);
        }
    };

    sel(Drgb, ORGB*L1N, state + 0,  thr + 0,  w1);
    sel(Dgray, OGRAY*L1N, state + 32, thr + 32, w1);

    k_tri_sfm1<<<31250, 256, 0, stream>>>(Drgb, Dgray, thr + 0, thr + 32, w1, X1p);
    k_z1<<<313, 256, 0, stream>>>(X1p, ws + O_ZP1);
    k_psq1<<<288, 256, 0, stream>>>(ws + O_ZP1, ws + O_PSQ1);

    float* D1 = ws + O_A;
    k_gemm<<<dim3(NT1/256, 2), 256, 0, stream>>>(c1w, X1p, koff1, ymf1, omap1,
        ws + O_PSQ1, ws + O_WSQ1, D1, M1, K1, K1P, P1, NT1);

    sel(D1, M1*P1, state + 64, thr + 64, w2);

    float* X2 = ws + O_B;
    k_tri_sfm2<<<16200, 256, 0, stream>>>(D1, thr + 64, w2, X2);
    k_z2<<<72, 256, 0, stream>>>(X2, ws + O_Z2);
    k_psq2<<<61, 256, 0, stream>>>(ws + O_Z2, ws + O_PSQ2);

    float* D2 = ws + O_A;
    k_gemm<<<dim3((NT2 + 255)/256, 5), 256, 0, stream>>>(c2w, X2, koff2, ymf2, omap2,
        ws + O_PSQ2, ws + O_WSQ2, D2, M2, K2, K2P, N2, NT2);

    sel(D2, FCN, state + 96, thr + 96, w3);

    k_fc<<<dim3(148, 32), 256, 0, stream>>>(D2, fcw, thr + 96, w3, out);
}

// Round 6
// 1431.279 us; speedup vs baseline: 4.6783x; 1.3896x over previous
//
#include <hip/hip_runtime.h>

typedef unsigned int uint;
typedef unsigned short ushort;

#define NB 32

// geometry
#define L1N 9216      // 96*96
#define ORGB 75
#define OGRAY 25
#define C1 100
#define PLANE1 2500   // 50*50 padded
#define P1 2304       // 48*48
#define M1 225
#define K1 900
#define K1C 928       // pad to mult of 32
#define P2 576        // 24*24
#define M2 625
#define K2 2025
#define K2C 2048
#define N2 484        // 22*22
#define FCN 302500    // 625*484
#define NT1 73728     // 2304*32 merged columns
#define NT2 15488     // 484*32 merged columns

// exact ranks: ceil(percent*N) evaluated in fp64
#define KK0 345600u
#define KK1 115200u
#define KK2 207360u
#define KK3 121000u

// ---- workspace layout (float-element offsets) ----
constexpr size_t O_A     = 0;                       // Drgb 22118400 / D1 16.6M / D2 9.7M
constexpr size_t O_B     = 22118400;                // Dgray 7372800 ; W-splits overlay after tri_sfm1
constexpr size_t O_WH1   = O_B;                     // 104400 floats (225*928 ushorts /2)
constexpr size_t O_WM1   = O_B + 104400;
constexpr size_t O_WL1   = O_B + 208800;
constexpr size_t O_WH2   = O_B + 313200;            // 640000 each (625*2048/2)
constexpr size_t O_WM2   = O_B + 953200;
constexpr size_t O_WL2   = O_B + 1593200;
constexpr size_t O_XS    = 29491200;                // X1 splits: 3 x 4,000,000 (8M ushorts each)
constexpr size_t O_XH1   = O_XS;
constexpr size_t O_XM1   = O_XS + 4000000;
constexpr size_t O_XL1   = O_XS + 8000000;
constexpr size_t O_XH2   = O_XS;                    // X2 splits overlay (2073600 each)
constexpr size_t O_XM2   = O_XS + 2073600;
constexpr size_t O_XL2   = O_XS + 4147200;
constexpr size_t O_HIST  = 41491200;                // 65536 uints
constexpr size_t O_STATE = 41556736;                // 128 uint2
constexpr size_t O_THR   = 41556992;                // 128
constexpr size_t O_WSQ1  = 41557120;                // 256
constexpr size_t O_WSQ2  = 41557376;                // 640
constexpr size_t O_KOFF1 = 41558016;                // 928 ints (16B aligned)
constexpr size_t O_KOFF2 = 41558944;                // 2048 ints
constexpr size_t O_YMF1  = 41560992;                // 73728
constexpr size_t O_OMAP1 = 41634720;                // 73728
constexpr size_t O_YMF2  = 41708448;                // 15488
constexpr size_t O_OMAP2 = 41723936;                // 15488
constexpr size_t O_ZP1   = 41739424;                // 80000
constexpr size_t O_PSQ1  = 41819424;                // 73728
constexpr size_t O_Z2    = 41893152;                // 18432
constexpr size_t O_PSQ2  = 41911584;                // 15488
constexpr size_t O_END   = 41927072;                // ~167.7 MB

// ---- bf16 helpers (RNE) ----
__device__ __forceinline__ ushort bf16_rne(float x) {
    uint u = __float_as_uint(x);
    uint r = u + 0x7FFFu + ((u >> 16) & 1u);
    return (ushort)(r >> 16);
}
__device__ __forceinline__ float bf16_f32(ushort h) {
    return __uint_as_float(((uint)h) << 16);
}
__device__ __forceinline__ void split3(float v, ushort& h, ushort& m, ushort& l) {
    h = bf16_rne(v);           float hf = bf16_f32(h);
    m = bf16_rne(v - hf);      float mf = bf16_f32(m);
    l = bf16_rne(v - hf - mf);
}

typedef __attribute__((ext_vector_type(8))) short bf16x8;
typedef __attribute__((ext_vector_type(4))) float f32x4;

// ===================== init: zero hist, states, tables, out=bias =====================
__global__ void k_tables(float* ws, const float* fcb, float* out) {
    int i = blockIdx.x*256 + threadIdx.x;
    if (i < 65536) { ((uint*)(ws + O_HIST))[i] = 0u; return; }
    i -= 65536;
    if (i < K1C) {
        int v = 0;
        if (i < K1) { int c = i/9, rm = i%9; v = c*PLANE1 + (rm/3)*50 + (rm%3); }
        ((int*)(ws + O_KOFF1))[i] = v; return;
    }
    i -= K1C;
    if (i < K2C) {
        int v = 0;
        if (i < K2) { int c = i/9, rm = i%9; v = c*P2 + (rm/3)*24 + (rm%3); }
        ((int*)(ws + O_KOFF2))[i] = v; return;
    }
    i -= K2C;
    if (i < NT1) {
        int b = i / P1, p = i % P1;
        ((int*)(ws + O_YMF1))[i]  = b*(C1*PLANE1) + (p/48)*50 + (p%48);
        ((int*)(ws + O_OMAP1))[i] = b*(M1*P1) + p;
        return;
    }
    i -= NT1;
    if (i < NT2) {
        int b = i / N2, p = i % N2;
        ((int*)(ws + O_YMF2))[i]  = b*(M1*P2) + (p/22)*24 + (p%22);
        ((int*)(ws + O_OMAP2))[i] = b*FCN + p;
        return;
    }
    i -= NT2;
    if (i < 320) { out[i] = fcb[i % 10]; return; }
    i -= 320;
    if (i < 128) {
        const uint kks[4] = {KK0, KK1, KK2, KK3};
        ((uint2*)(ws + O_STATE))[i] = make_uint2(0u, kks[i >> 5]);
    }
}

// ===================== per-row squared norms of conv weights =====================
__global__ void k_wsq(const float* c1w, const float* c2w, float* ws) {
    int o = blockIdx.x, lane = threadIdx.x;   // 64 threads
    const float* row; int K; float* dst;
    if (o < M1) { row = c1w + (size_t)o*K1; K = K1; dst = ws + O_WSQ1 + o; }
    else { int oo = o - M1; row = c2w + (size_t)oo*K2; K = K2; dst = ws + O_WSQ2 + oo; }
    float s = 0.f;
    for (int k = lane; k < K; k += 64) { float v = row[k]; s += v*v; }
    #pragma unroll
    for (int off = 32; off; off >>= 1) s += __shfl_down(s, off);
    if (lane == 0) *dst = s;
}

// ===================== split W into bf16 h/m/l planes (runs after tri_sfm1) =====================
__global__ void k_splitw(const float* __restrict__ c1w, const float* __restrict__ c2w,
                         float* __restrict__ ws) {
    int i = blockIdx.x*256 + threadIdx.x;
    ushort h, m, l;
    if (i < M1*K1C) {
        int r = i / K1C, k = i % K1C;
        float x = (k < K1) ? c1w[(size_t)r*K1 + k] : 0.f;
        split3(x, h, m, l);
        ((ushort*)(ws + O_WH1))[i] = h;
        ((ushort*)(ws + O_WM1))[i] = m;
        ((ushort*)(ws + O_WL1))[i] = l;
        return;
    }
    i -= M1*K1C;
    if (i < M2*K2C) {
        int r = i / K2C, k = i % K2C;
        float x = (k < K2) ? c2w[(size_t)r*K2 + k] : 0.f;
        split3(x, h, m, l);
        ((ushort*)(ws + O_WH2))[i] = h;
        ((ushort*)(ws + O_WM2))[i] = m;
        ((ushort*)(ws + O_WL2))[i] = l;
    }
}

// ===================== stage 1: rgb distance =====================
__global__ void k_rgb_d(const float* __restrict__ x, const float* __restrict__ rgbw,
                        float* __restrict__ D) {
    __shared__ float lw[ORGB*3];
    __shared__ float lwsq[ORGB];
    int tid = threadIdx.x;
    if (tid < ORGB*3) lw[tid] = rgbw[tid];
    __syncthreads();
    if (tid < ORGB) {
        float a = lw[tid*3], b = lw[tid*3+1], c = lw[tid*3+2];
        lwsq[tid] = 25.0f*(a*a + b*b + c*c);
    }
    __syncthreads();
    int p = blockIdx.x*256 + tid;
    int b = blockIdx.y;
    int y = p / 96, xx = p % 96;
    const float* xb = x + (size_t)b*3*10000;
    float s1_0 = 0, s1_1 = 0, s1_2 = 0, s2 = 0;
    #pragma unroll
    for (int r = 0; r < 5; ++r)
        #pragma unroll
        for (int s = 0; s < 5; ++s) {
            int off = (y+r)*100 + (xx+s);
            float v0 = xb[off], v1 = xb[10000+off], v2 = xb[20000+off];
            s1_0 += v0; s1_1 += v1; s1_2 += v2;
            s2 += v0*v0 + v1*v1 + v2*v2;
        }
    float* Db = D + (size_t)b*ORGB*L1N + p;
    for (int o = 0; o < ORGB; ++o) {
        float dot = lw[o*3]*s1_0 + lw[o*3+1]*s1_1 + lw[o*3+2]*s1_2;
        float d2 = s2 + lwsq[o] - 2.0f*dot;
        Db[(size_t)o*L1N] = sqrtf(fmaxf(d2, 0.0f));
    }
}

// ===================== stage 1: gray distance =====================
__global__ void k_gray_d(const float* __restrict__ x, const float* __restrict__ gw,
                         float* __restrict__ D) {
    __shared__ float lw[625];
    __shared__ float lwsq[25];
    int tid = threadIdx.x;
    for (int i = tid; i < 625; i += 256) lw[i] = gw[i];
    __syncthreads();
    if (tid < 25) {
        float s = 0.f;
        for (int k = 0; k < 25; ++k) { float v = lw[tid*25+k]; s += v*v; }
        lwsq[tid] = s;
    }
    __syncthreads();
    int p = blockIdx.x*256 + tid;
    int b = blockIdx.y;
    int y = p / 96, xx = p % 96;
    const float* xb = x + (size_t)b*3*10000;
    float pv[25]; float psum = 0.f;
    #pragma unroll
    for (int r = 0; r < 5; ++r)
        #pragma unroll
        for (int s = 0; s < 5; ++s) {
            int off = (y+r)*100 + (xx+s);
            float g = 0.2989f*xb[off] + 0.587f*xb[10000+off] + 0.114f*xb[20000+off];
            pv[r*5+s] = g; psum += g*g;
        }
    float* Db = D + (size_t)b*OGRAY*L1N + p;
    for (int o = 0; o < 25; ++o) {
        float dot = 0.f;
        #pragma unroll
        for (int k = 0; k < 25; ++k) dot += lw[o*25+k]*pv[k];
        float d2 = psum + lwsq[o] - 2.0f*dot;
        Db[(size_t)o*L1N] = sqrtf(fmaxf(d2, 0.0f));
    }
}

// ===================== exact rank selection: histogram pass =====================
__global__ void k_hist(const float* __restrict__ d, int perBatch, uint* __restrict__ hist,
                       const uint2* __restrict__ state, int shift, uint pmask) {
    __shared__ uint lh[2048];
    int tid = threadIdx.x;
    for (int i = tid; i < 2048; i += 256) lh[i] = 0u;
    __syncthreads();
    int b = blockIdx.y;
    uint pref = state[b].x;
    const float* db = d + (size_t)b*perBatch;
    for (int i = blockIdx.x*256 + tid; i < perBatch; i += 256*32) {
        uint bits = __float_as_uint(db[i]);
        if ((bits & pmask) == pref)
            atomicAdd(&lh[(bits >> shift) & 2047u], 1u);
    }
    __syncthreads();
    uint* hb = hist + (size_t)b*2048;
    for (int i = tid; i < 2048; i += 256) {
        uint v = lh[i];
        if (v) atomicAdd(&hb[i], v);
    }
}

// ===================== selection: scan + state update (+zero hist) =====================
__global__ void k_scan(uint* __restrict__ hist, uint2* __restrict__ state, int shift,
                       int isFinal, float* __restrict__ thr_out, const float* __restrict__ wcap) {
    __shared__ uint ss[256];
    int b = blockIdx.x, t = threadIdx.x;
    uint* hb = hist + (size_t)b*2048;
    uint bins[8]; uint seg = 0;
    #pragma unroll
    for (int i = 0; i < 8; ++i) { bins[i] = hb[t*8+i]; seg += bins[i]; }
    ss[t] = seg;
    __syncthreads();
    for (int off = 1; off < 256; off <<= 1) {
        uint add = (t >= off) ? ss[t-off] : 0u;
        __syncthreads();
        ss[t] += add;
        __syncthreads();
    }
    uint incl = ss[t], excl = incl - seg;
    uint rank = state[b].y;
    if (excl < rank && rank <= incl) {
        uint c = excl;
        #pragma unroll
        for (int i = 0; i < 8; ++i) {
            c += bins[i];
            if (c >= rank) {
                uint bin = (uint)(t*8+i);
                uint pref = state[b].x | (bin << shift);
                if (isFinal) {
                    thr_out[b] = fminf(__uint_as_float(pref), wcap[0]);
                } else {
                    state[b] = make_uint2(pref, rank - (c - bins[i]));
                }
                break;
            }
        }
    }
    __syncthreads();
    #pragma unroll
    for (int i = 0; i < 8; ++i) hb[t*8+i] = 0u;
}

// ===================== triangle + concat + sfm(2,2) -> X1 split planes =====================
__global__ void k_tri_sfm1(const float* __restrict__ Drgb, const float* __restrict__ Dgray,
                           const float* __restrict__ thrA, const float* __restrict__ thrB,
                           const float* __restrict__ w1, ushort* __restrict__ XH,
                           ushort* __restrict__ XM, ushort* __restrict__ XL) {
    int idx = blockIdx.x*256 + threadIdx.x;   // exactly 32*100*2500
    int b = idx / (C1*PLANE1);
    int rem = idx % (C1*PLANE1);
    int c = rem / PLANE1;
    int q = rem % PLANE1;
    int pi = q / 50, pj = q % 50;
    if (pi == 0 || pi == 49 || pj == 0 || pj == 49) {
        XH[idx] = 0; XM[idx] = 0; XL[idx] = 0; return;
    }
    int i = pi - 1, j = pj - 1;
    const float* src; float thr;
    if (c < ORGB) { src = Drgb + ((size_t)b*ORGB + c)*L1N; thr = thrA[b]; }
    else          { src = Dgray + ((size_t)b*OGRAY + (c-ORGB))*L1N; thr = thrB[b]; }
    float invw = 1.0f / w1[0];
    int base = (2*i)*96 + 2*j;
    float d00 = src[base], d01 = src[base+1], d10 = src[base+96], d11 = src[base+97];
    float t00 = d00 > thr ? 0.f : 1.f - d00*invw;
    float t01 = d01 > thr ? 0.f : 1.f - d01*invw;
    float t10 = d10 > thr ? 0.f : 1.f - d10*invw;
    float t11 = d11 > thr ? 0.f : 1.f - d11*invw;
    float v = 0.25f*(0.9f*t00 + 0.93f*t01 + 0.96f*t10 + 0.99f*t11);
    ushort h, m, l; split3(v, h, m, l);
    XH[idx] = h; XM[idx] = m; XL[idx] = l;
}

// ===================== channel-sum of squares (padded plane, from splits) =====================
__global__ void k_z1(const ushort* __restrict__ XH, const ushort* __restrict__ XM,
                     const ushort* __restrict__ XL, float* __restrict__ Zp) {
    int idx = blockIdx.x*256 + threadIdx.x;
    if (idx >= NB*PLANE1) return;
    int b = idx / PLANE1, q = idx % PLANE1;
    size_t base = (size_t)b*C1*PLANE1 + q;
    float s = 0.f;
    for (int c = 0; c < C1; ++c) {
        size_t o = base + (size_t)c*PLANE1;
        float v = bf16_f32(XH[o]) + bf16_f32(XM[o]) + bf16_f32(XL[o]);
        s += v*v;
    }
    Zp[idx] = s;
}

__global__ void k_psq1(const float* __restrict__ Zp, float* __restrict__ psq) {
    int idx = blockIdx.x*256 + threadIdx.x;   // exactly 32*2304
    int b = idx / P1, p = idx % P1;
    int y = p / 48, x = p % 48;
    const float* zb = Zp + (size_t)b*PLANE1;
    float s = 0.f;
    #pragma unroll
    for (int r = 0; r < 3; ++r)
        #pragma unroll
        for (int c = 0; c < 3; ++c) s += zb[(y+r)*50 + x + c];
    psq[idx] = s;
}

// ===================== MFMA GEMM: D = sqrt(psq + wsq - 2*W.X) via bf16 3-split =====================
// block tile 128(M) x 192(N), K-chunk 32, 4 waves (2x2) of 4x6 16x16-tiles.
// 6 products (hh,hm,mh,hl,lh,mm): error O(2^-24) -> fp32-equivalent.
// A (W-splits) read direct from global (L1-hot); B (X-splits) gathered im2col -> LDS frag-major.
__global__ __launch_bounds__(256, 2) void k_gemm_mfma(
        const ushort* __restrict__ Wh, const ushort* __restrict__ Wm, const ushort* __restrict__ Wl,
        const ushort* __restrict__ Xh, const ushort* __restrict__ Xm, const ushort* __restrict__ Xl,
        const int* __restrict__ koff, const int* __restrict__ ymapF, const int* __restrict__ omap,
        const float* __restrict__ psq, const float* __restrict__ wsq, float* __restrict__ Dout,
        int M, int KC, int Nper, int NT) {
    __shared__ ushort Bs[3*12*64*8];     // 36 KB: [split][ntile 12][lane 64][8]
    __shared__ float psl[192];
    __shared__ int   outl[192];

    int tid = threadIdx.x;
    int n0 = blockIdx.x*192; if (n0 + 192 > NT) n0 = NT - 192;   // overlap: dup writes identical
    int m0 = blockIdx.y*128;
    int lane = tid & 63, wid = tid >> 6;
    int wy = wid >> 1, wx = wid & 1;

    if (tid < 192) { psl[tid] = psq[n0+tid]; outl[tid] = omap[n0+tid]; }

    // gather geometry: 3 (ntile,lane') slots per thread, shared across the 3 splits
    int ntg[3], lp[3], yv[3];
    #pragma unroll
    for (int b = 0; b < 3; ++b) {
        int idx = b*256 + tid;              // 0..767 = 12 ntiles x 64 lanes
        ntg[b] = idx >> 6; lp[b] = idx & 63;
        yv[b] = ymapF[n0 + ntg[b]*16 + (lp[b] & 15)];
    }

    // A-frag element offsets per m-tile (row-clamped; frag k-base = quad*8)
    int rowOff[4];
    #pragma unroll
    for (int mt = 0; mt < 4; ++mt) {
        int r = m0 + wy*64 + mt*16 + (lane & 15);
        if (r > M-1) r = M-1;
        rowOff[mt] = r*KC + ((lane >> 4) << 3);
    }

    f32x4 acc[4][6];
    #pragma unroll
    for (int mt = 0; mt < 4; ++mt)
        #pragma unroll
        for (int nt = 0; nt < 6; ++nt) acc[mt][nt] = (f32x4){0.f, 0.f, 0.f, 0.f};

    uint4 g[9];   // staged gathers: [base 3][split 3] -> 8 bf16 each
    auto GATHER = [&](int kc) {
        #pragma unroll
        for (int b = 0; b < 3; ++b) {
            int kq = lp[b] >> 4;
            const int4* kp = (const int4*)(koff + (kc << 5) + (kq << 3));
            int4 ka = kp[0], kb = kp[1];
            int o0 = ka.x + yv[b], o1 = ka.y + yv[b], o2 = ka.z + yv[b], o3 = ka.w + yv[b];
            int o4 = kb.x + yv[b], o5 = kb.y + yv[b], o6 = kb.z + yv[b], o7 = kb.w + yv[b];
            uint4 gh, gm, gl;
            gh.x = (uint)Xh[o0] | ((uint)Xh[o1] << 16);
            gh.y = (uint)Xh[o2] | ((uint)Xh[o3] << 16);
            gh.z = (uint)Xh[o4] | ((uint)Xh[o5] << 16);
            gh.w = (uint)Xh[o6] | ((uint)Xh[o7] << 16);
            gm.x = (uint)Xm[o0] | ((uint)Xm[o1] << 16);
            gm.y = (uint)Xm[o2] | ((uint)Xm[o3] << 16);
            gm.z = (uint)Xm[o4] | ((uint)Xm[o5] << 16);
            gm.w = (uint)Xm[o6] | ((uint)Xm[o7] << 16);
            gl.x = (uint)Xl[o0] | ((uint)Xl[o1] << 16);
            gl.y = (uint)Xl[o2] | ((uint)Xl[o3] << 16);
            gl.z = (uint)Xl[o4] | ((uint)Xl[o5] << 16);
            gl.w = (uint)Xl[o6] | ((uint)Xl[o7] << 16);
            g[b*3+0] = gh; g[b*3+1] = gm; g[b*3+2] = gl;
        }
    };

    GATHER(0);
    const ushort* Wp0 = Wh; const ushort* Wp1 = Wm; const ushort* Wp2 = Wl;

    int nch = KC >> 5;
    for (int kc = 0; kc < nch; ++kc) {
        __syncthreads();                     // prior chunk's B-frag reads complete
        #pragma unroll
        for (int b = 0; b < 3; ++b)
            #pragma unroll
            for (int s = 0; s < 3; ++s)
                *(uint4*)&Bs[(((s*12 + ntg[b]) << 6) + lp[b]) << 3] = g[b*3+s];
        __syncthreads();                     // writes visible
        if (kc + 1 < nch) GATHER(kc + 1);

        int kel = kc << 5;                   // chunk element base in K
        // product pairs: (W-split, X-split) = (h,h),(h,m),(m,h),(h,l),(l,h),(m,m)
        #pragma unroll
        for (int p = 0; p < 6; ++p) {
            const ushort* Wsrc = (p == 2 || p == 5) ? Wp1 : ((p == 4) ? Wp2 : Wp0);
            const int sb = (p == 1) ? 1 : ((p == 3) ? 2 : ((p == 5) ? 1 : 0));
            bf16x8 bf[6];
            #pragma unroll
            for (int nt = 0; nt < 6; ++nt)
                bf[nt] = *(const bf16x8*)&Bs[((((sb*12 + wx*6 + nt) << 6) + lane) << 3)];
            #pragma unroll
            for (int mt = 0; mt < 4; ++mt) {
                bf16x8 af = *(const bf16x8*)(Wsrc + rowOff[mt] + kel);
                #pragma unroll
                for (int nt = 0; nt < 6; ++nt)
                    acc[mt][nt] = __builtin_amdgcn_mfma_f32_16x16x32_bf16(af, bf[nt], acc[mt][nt], 0, 0, 0);
            }
        }
    }

    // epilogue: C/D layout col=lane&15, row=quad*4+reg  [verified m89/m91]
    int quad = lane >> 4;
    #pragma unroll
    for (int mt = 0; mt < 4; ++mt) {
        int gmb = m0 + wy*64 + mt*16 + (quad << 2);
        float4 w4 = *(const float4*)&wsq[gmb];
        #pragma unroll
        for (int nt = 0; nt < 6; ++nt) {
            int nl = wx*96 + nt*16 + (lane & 15);
            float ps = psl[nl];
            size_t ob = (size_t)outl[nl];
            f32x4 a = acc[mt][nt];
            if (gmb + 0 < M) Dout[ob + (size_t)(gmb+0)*Nper] = sqrtf(fmaxf(ps + w4.x - 2.0f*a.x, 0.f));
            if (gmb + 1 < M) Dout[ob + (size_t)(gmb+1)*Nper] = sqrtf(fmaxf(ps + w4.y - 2.0f*a.y, 0.f));
            if (gmb + 2 < M) Dout[ob + (size_t)(gmb+2)*Nper] = sqrtf(fmaxf(ps + w4.z - 2.0f*a.z, 0.f));
            if (gmb + 3 < M) Dout[ob + (size_t)(gmb+3)*Nper] = sqrtf(fmaxf(ps + w4.w - 2.0f*a.w, 0.f));
        }
    }
}

// ===================== triangle + sfm(2,2) after conv1 -> X2 split planes =====================
__global__ void k_tri_sfm2(const float* __restrict__ D1, const float* __restrict__ thr2,
                           const float* __restrict__ w2, ushort* __restrict__ XH,
                           ushort* __restrict__ XM, ushort* __restrict__ XL) {
    int idx = blockIdx.x*256 + threadIdx.x;   // exactly 32*225*576
    int b = idx / (M1*P2);
    int rem = idx % (M1*P2);
    int c = rem / P2, q = rem % P2;
    int i = q / 24, j = q % 24;
    const float* src = D1 + ((size_t)b*M1 + c)*P1;
    float thr = thr2[b], invw = 1.0f / w2[0];
    int base = (2*i)*48 + 2*j;
    float d00 = src[base], d01 = src[base+1], d10 = src[base+48], d11 = src[base+49];
    float t00 = d00 > thr ? 0.f : 1.f - d00*invw;
    float t01 = d01 > thr ? 0.f : 1.f - d01*invw;
    float t10 = d10 > thr ? 0.f : 1.f - d10*invw;
    float t11 = d11 > thr ? 0.f : 1.f - d11*invw;
    float v = 0.25f*(0.9f*t00 + 0.93f*t01 + 0.96f*t10 + 0.99f*t11);
    ushort h, m, l; split3(v, h, m, l);
    XH[idx] = h; XM[idx] = m; XL[idx] = l;
}

__global__ void k_z2(const ushort* __restrict__ XH, const ushort* __restrict__ XM,
                     const ushort* __restrict__ XL, float* __restrict__ Z2) {
    int idx = blockIdx.x*256 + threadIdx.x;
    if (idx >= NB*P2) return;
    int b = idx / P2, q = idx % P2;
    size_t base = (size_t)b*M1*P2 + q;
    float s = 0.f;
    for (int c = 0; c < M1; ++c) {
        size_t o = base + (size_t)c*P2;
        float v = bf16_f32(XH[o]) + bf16_f32(XM[o]) + bf16_f32(XL[o]);
        s += v*v;
    }
    Z2[idx] = s;
}

__global__ void k_psq2(const float* __restrict__ Z2, float* __restrict__ psq) {
    int idx = blockIdx.x*256 + threadIdx.x;
    if (idx >= NB*N2) return;
    int b = idx / N2, p = idx % N2;
    int y = p / 22, x = p % 22;
    const float* zb = Z2 + (size_t)b*P2;
    float s = 0.f;
    #pragma unroll
    for (int r = 0; r < 3; ++r)
        #pragma unroll
        for (int c = 0; c < 3; ++c) s += zb[(y+r)*24 + x + c];
    psq[idx] = s;
}

// ===================== triangle + FC =====================
__global__ void k_fc(const float* __restrict__ D2, const float* __restrict__ fcw,
                     const float* __restrict__ thr3, const float* __restrict__ w3,
                     float* __restrict__ out) {
    int tid = threadIdx.x, b = blockIdx.y;
    float thr = thr3[b];
    float invw = 1.0f / w3[0];
    const float* db = D2 + (size_t)b*FCN;
    float acc[10];
    #pragma unroll
    for (int o = 0; o < 10; ++o) acc[o] = 0.f;
    int base = blockIdx.x*2048;
    #pragma unroll
    for (int it = 0; it < 8; ++it) {
        int p = base + it*256 + tid;
        if (p < FCN) {
            float v = db[p];
            float tv = v > thr ? 0.f : 1.f - v*invw;
            #pragma unroll
            for (int o = 0; o < 10; ++o) acc[o] += tv * fcw[(size_t)o*FCN + p];
        }
    }
    #pragma unroll
    for (int o = 0; o < 10; ++o)
        #pragma unroll
        for (int off = 32; off; off >>= 1) acc[o] += __shfl_down(acc[o], off);
    __shared__ float red[4][10];
    int lane = tid & 63, wid = tid >> 6;
    if (lane == 0) {
        #pragma unroll
        for (int o = 0; o < 10; ++o) red[wid][o] = acc[o];
    }
    __syncthreads();
    if (tid < 10) {
        float s = red[0][tid] + red[1][tid] + red[2][tid] + red[3][tid];
        atomicAdd(&out[b*10 + tid], s);
    }
}

// ===================== launch =====================
extern "C" void kernel_launch(void* const* d_in, const int* in_sizes, int n_in,
                              void* d_out, int out_size, void* d_ws, size_t ws_size,
                              hipStream_t stream) {
    const float* x    = (const float*)d_in[0];
    const float* rgbw = (const float*)d_in[1];
    const float* gryw = (const float*)d_in[2];
    const float* c1w  = (const float*)d_in[3];
    const float* c2w  = (const float*)d_in[4];
    const float* fcw  = (const float*)d_in[5];
    const float* fcb  = (const float*)d_in[6];
    const float* w1   = (const float*)d_in[7];
    const float* w2   = (const float*)d_in[8];
    const float* w3   = (const float*)d_in[9];
    float* out = (float*)d_out;
    float* ws  = (float*)d_ws;

    float* Drgb  = ws + O_A;
    float* Dgray = ws + O_B;
    uint*  hist  = (uint*)(ws + O_HIST);
    uint2* state = (uint2*)(ws + O_STATE);
    float* thr   = ws + O_THR;
    int* koff1 = (int*)(ws + O_KOFF1);
    int* koff2 = (int*)(ws + O_KOFF2);
    int* ymf1  = (int*)(ws + O_YMF1);
    int* omap1 = (int*)(ws + O_OMAP1);
    int* ymf2  = (int*)(ws + O_YMF2);
    int* omap2 = (int*)(ws + O_OMAP2);

    // init threads: 65536+928+2048+73728+15488+320+128 = 158176 -> 618 blocks
    k_tables<<<618, 256, 0, stream>>>(ws, fcb, out);
    k_wsq<<<M1 + M2, 64, 0, stream>>>(c1w, c2w, ws);
    k_rgb_d<<<dim3(36, 32), 256, 0, stream>>>(x, rgbw, Drgb);
    k_gray_d<<<dim3(36, 32), 256, 0, stream>>>(x, gryw, Dgray);

    auto sel = [&](const float* dptr, int perBatch, uint2* st, float* thro, const float* wc) {
        const int shifts[3] = {21, 10, 0};
        const uint masks[3] = {0u, 0xFFE00000u, 0xFFFFFC00u};
        for (int p = 0; p < 3; ++p) {
            k_hist<<<dim3(32, 32), 256, 0, stream>>>(dptr, perBatch, hist, st, shifts[p], masks[p]);
            k_scan<<<32, 256, 0, stream>>>(hist, st, shifts[p], p == 2, thro, wc);
        }
    };

    sel(Drgb, ORGB*L1N, state + 0,  thr + 0,  w1);
    sel(Dgray, OGRAY*L1N, state + 32, thr + 32, w1);

    k_tri_sfm1<<<31250, 256, 0, stream>>>(Drgb, Dgray, thr + 0, thr + 32, w1,
        (ushort*)(ws + O_XH1), (ushort*)(ws + O_XM1), (ushort*)(ws + O_XL1));
    // W-splits overlay the (now dead) Dgray region
    k_splitw<<<5816, 256, 0, stream>>>(c1w, c2w, ws);
    k_z1<<<313, 256, 0, stream>>>((const ushort*)(ws + O_XH1), (const ushort*)(ws + O_XM1),
        (const ushort*)(ws + O_XL1), ws + O_ZP1);
    k_psq1<<<288, 256, 0, stream>>>(ws + O_ZP1, ws + O_PSQ1);

    float* D1 = ws + O_A;
    k_gemm_mfma<<<dim3(NT1/192, 2), 256, 0, stream>>>(
        (const ushort*)(ws + O_WH1), (const ushort*)(ws + O_WM1), (const ushort*)(ws + O_WL1),
        (const ushort*)(ws + O_XH1), (const ushort*)(ws + O_XM1), (const ushort*)(ws + O_XL1),
        koff1, ymf1, omap1, ws + O_PSQ1, ws + O_WSQ1, D1, M1, K1C, P1, NT1);

    sel(D1, M1*P1, state + 64, thr + 64, w2);

    k_tri_sfm2<<<16200, 256, 0, stream>>>(D1, thr + 64, w2,
        (ushort*)(ws + O_XH2), (ushort*)(ws + O_XM2), (ushort*)(ws + O_XL2));
    k_z2<<<72, 256, 0, stream>>>((const ushort*)(ws + O_XH2), (const ushort*)(ws + O_XM2),
        (const ushort*)(ws + O_XL2), ws + O_Z2);
    k_psq2<<<61, 256, 0, stream>>>(ws + O_Z2, ws + O_PSQ2);

    float* D2 = ws + O_A;
    k_gemm_mfma<<<dim3((NT2 + 191)/192, 5), 256, 0, stream>>>(
        (const ushort*)(ws + O_WH2), (const ushort*)(ws + O_WM2), (const ushort*)(ws + O_WL2),
        (const ushort*)(ws + O_XH2), (const ushort*)(ws + O_XM2), (const ushort*)(ws + O_XL2),
        koff2, ymf2, omap2, ws + O_PSQ2, ws + O_WSQ2, D2, M2, K2C, N2, NT2);

    sel(D2, FCN, state + 96, thr + 96, w3);

    k_fc<<<dim3(148, 32), 256, 0, stream>>>(D2, fcw, thr + 96, w3, out);
}